// Round 1
// baseline (1091.917 us; speedup 1.0000x reference)
//
#include <hip/hip_runtime.h>
#include <math.h>

#define CH 512
#define HWP 1024
#define NTOK 1032
#define NPRM 8
#define HD 64
#define BB 4
#define EPSV 1e-5f

__device__ __forceinline__ float gelu_f(float x) {
  return 0.5f * x * (1.0f + erff(x * 0.70710678118654752440f));
}

// ---------------- depthwise 3x3 + BN + GELU ----------------
__global__ __launch_bounds__(256) void dw_bn_gelu(
    const float* __restrict__ in, const float* __restrict__ w,
    const float* __restrict__ bn, float* __restrict__ out)
{
  int bc = blockIdx.x;            // b*512 + c
  int c = bc & (CH - 1);
  float w9[9];
  #pragma unroll
  for (int i = 0; i < 9; ++i) w9[i] = w[c * 9 + i];
  float g = bn[c], be = bn[CH + c], mm = bn[2 * CH + c], vv = bn[3 * CH + c];
  float s = g * rsqrtf(vv + EPSV);
  float sh = be - mm * s;
  const float* ip = in + (size_t)bc * HWP;
  float* op = out + (size_t)bc * HWP;
  for (int px = threadIdx.x; px < HWP; px += 256) {
    int y = px >> 5, x = px & 31;
    float acc = 0.0f;
    #pragma unroll
    for (int dy = 0; dy < 3; ++dy) {
      int yy = y + dy - 1;
      if ((unsigned)yy < 32u) {
        #pragma unroll
        for (int dx = 0; dx < 3; ++dx) {
          int xx = x + dx - 1;
          if ((unsigned)xx < 32u) acc += ip[yy * 32 + xx] * w9[dy * 3 + dx];
        }
      }
    }
    op[px] = gelu_f(acc * s + sh);
  }
}

// ---------------- pointwise conv GEMM: out[b,o,hw] = epi(sum_c W[o,c]*In[b,c,hw]) ----------------
// mode 0: BN + GELU; mode 1: BN + residual add (res has same layout as out)
__global__ __launch_bounds__(256) void pw_gemm(
    const float* __restrict__ W, const float* __restrict__ In,
    float* Out, const float* __restrict__ bn,
    const float* res, int mode)
{
  __shared__ __align__(16) float Ws[32][64];
  __shared__ __align__(16) float Is[32][64];
  int t = threadIdx.x;
  int tx = t & 15, ty = t >> 4;
  int n0 = blockIdx.x * 64;       // hw
  int o0 = blockIdx.y * 64;       // out channel
  int b = blockIdx.z;
  const float* inb = In + (size_t)b * CH * HWP;
  float acc[4][4] = {};
  for (int k0 = 0; k0 < CH; k0 += 32) {
    __syncthreads();
    #pragma unroll
    for (int L = 0; L < 2; ++L) {
      int idx = t + 256 * L;            // 0..511
      int r = idx >> 3;                  // 0..63
      int kc = (idx & 7) << 2;           // 0..28
      float4 va = *(const float4*)&W[(size_t)(o0 + r) * CH + k0 + kc];
      Ws[kc + 0][r] = va.x; Ws[kc + 1][r] = va.y; Ws[kc + 2][r] = va.z; Ws[kc + 3][r] = va.w;
      int r2 = idx >> 4;                 // 0..31
      int c2 = (idx & 15) << 2;          // 0..60
      float4 vb = *(const float4*)&inb[(size_t)(k0 + r2) * HWP + n0 + c2];
      *(float4*)&Is[r2][c2] = vb;
    }
    __syncthreads();
    #pragma unroll
    for (int kk = 0; kk < 32; ++kk) {
      float4 a4 = *(const float4*)&Ws[kk][ty * 4];
      float4 b4 = *(const float4*)&Is[kk][tx * 4];
      acc[0][0] += a4.x * b4.x; acc[0][1] += a4.x * b4.y; acc[0][2] += a4.x * b4.z; acc[0][3] += a4.x * b4.w;
      acc[1][0] += a4.y * b4.x; acc[1][1] += a4.y * b4.y; acc[1][2] += a4.y * b4.z; acc[1][3] += a4.y * b4.w;
      acc[2][0] += a4.z * b4.x; acc[2][1] += a4.z * b4.y; acc[2][2] += a4.z * b4.z; acc[2][3] += a4.z * b4.w;
      acc[3][0] += a4.w * b4.x; acc[3][1] += a4.w * b4.y; acc[3][2] += a4.w * b4.z; acc[3][3] += a4.w * b4.w;
    }
  }
  float s[4], sh[4];
  #pragma unroll
  for (int i = 0; i < 4; ++i) {
    int o = o0 + ty * 4 + i;
    float g = bn[o], be = bn[CH + o], mm = bn[2 * CH + o], vv = bn[3 * CH + o];
    s[i] = g * rsqrtf(vv + EPSV);
    sh[i] = be - mm * s[i];
  }
  #pragma unroll
  for (int i = 0; i < 4; ++i) {
    int o = o0 + ty * 4 + i;
    #pragma unroll
    for (int j = 0; j < 4; ++j) {
      int hw = n0 + tx * 4 + j;
      float val = acc[i][j] * s[i] + sh[i];
      size_t oi = ((size_t)b * CH + o) * HWP + hw;
      if (mode == 0) Out[oi] = gelu_f(val);
      else Out[oi] = res[oi] + val;
    }
  }
}

// ---------------- pp pooling: per (b,c) 8 region means ----------------
__global__ __launch_bounds__(128) void pp_pool(const float* __restrict__ pp, float* __restrict__ ppool)
{
  int bc = blockIdx.x;          // b*512 + c
  int b = bc >> 9, c = bc & 511;
  __shared__ float sums[8];
  if (threadIdx.x < 8) sums[threadIdx.x] = 0.0f;
  __syncthreads();
  const float* ip = pp + (size_t)bc * HWP;
  float s0 = 0.0f, s1 = 0.0f;
  #pragma unroll
  for (int kq = 0; kq < 8; ++kq) {
    float val = ip[threadIdx.x + kq * 128];
    if (kq < 4) s0 += val; else s1 += val;
  }
  int pxr = (threadIdx.x & 31) >> 3;
  atomicAdd(&sums[pxr], s0);
  atomicAdd(&sums[4 + pxr], s1);
  __syncthreads();
  if (threadIdx.x < 8)
    ppool[((size_t)b * 8 + threadIdx.x) * CH + c] = sums[threadIdx.x] * (1.0f / 128.0f);
}

// ---------------- prompt: + embed, LayerNorm -> jt rows 0..7 ----------------
__global__ __launch_bounds__(128) void prompt_ln(
    const float* __restrict__ ppool, const float* __restrict__ embed,
    const float* __restrict__ lnp, float* __restrict__ jt)
{
  int r = blockIdx.x;           // b*8+p
  int b = r >> 3, p = r & 7;
  float4 val = ((const float4*)(ppool + (size_t)r * CH))[threadIdx.x];
  float4 e = ((const float4*)(embed + (size_t)p * CH))[threadIdx.x];
  val.x += e.x; val.y += e.y; val.z += e.z; val.w += e.w;
  float sum = val.x + val.y + val.z + val.w;
  float sq = val.x * val.x + val.y * val.y + val.z * val.z + val.w * val.w;
  #pragma unroll
  for (int off = 1; off < 64; off <<= 1) { sum += __shfl_xor(sum, off); sq += __shfl_xor(sq, off); }
  __shared__ float s2[4];
  if ((threadIdx.x & 63) == 0) { s2[(threadIdx.x >> 6) * 2] = sum; s2[(threadIdx.x >> 6) * 2 + 1] = sq; }
  __syncthreads();
  sum = s2[0] + s2[2]; sq = s2[1] + s2[3];
  float mu = sum * (1.0f / 512.0f);
  float var = sq * (1.0f / 512.0f) - mu * mu;
  float rstd = rsqrtf(var + EPSV);
  int c = threadIdx.x * 4;
  float4 o;
  o.x = (val.x - mu) * rstd * lnp[c] + lnp[CH + c];
  o.y = (val.y - mu) * rstd * lnp[c + 1] + lnp[CH + c + 1];
  o.z = (val.z - mu) * rstd * lnp[c + 2] + lnp[CH + c + 2];
  o.w = (val.w - mu) * rstd * lnp[c + 3] + lnp[CH + c + 3];
  ((float4*)(jt + ((size_t)(b * NTOK + p)) * CH))[threadIdx.x] = o;
}

// ---------------- gp pointwise (C->1) -> jd image part ----------------
__global__ __launch_bounds__(256) void gp_pw(
    const float* __restrict__ in, const float* __restrict__ w,
    const float* __restrict__ b0, float* __restrict__ jd)
{
  int b = blockIdx.y;
  int hw = blockIdx.x * 256 + threadIdx.x;
  __shared__ float ws[CH];
  ws[threadIdx.x] = w[threadIdx.x];
  ws[256 + threadIdx.x] = w[256 + threadIdx.x];
  __syncthreads();
  const float* ip = in + (size_t)b * CH * HWP + hw;
  float acc = 0.0f;
  for (int c = 0; c < CH; ++c) acc += ws[c] * ip[(size_t)c * HWP];
  jd[b * NTOK + NPRM + hw] = acc + b0[0];
}

// ---------------- jd prompt pooling ----------------
__global__ __launch_bounds__(256) void jd_pool(float* jd)
{
  int b = blockIdx.x;
  __shared__ float sums[8];
  if (threadIdx.x < 8) sums[threadIdx.x] = 0.0f;
  __syncthreads();
  #pragma unroll
  for (int kq = 0; kq < 4; ++kq) {
    int px = threadIdx.x + kq * 256;
    int y = px >> 5, x = px & 31;
    int r = (y >> 4) * 4 + (x >> 3);
    atomicAdd(&sums[r], jd[b * NTOK + NPRM + px]);
  }
  __syncthreads();
  if (threadIdx.x < 8) jd[b * NTOK + threadIdx.x] = sums[threadIdx.x] * (1.0f / 128.0f);
}

// ---------------- img tokens: jt[b,8+hw,c] = fused[b,c,hw] ----------------
__global__ __launch_bounds__(256) void img_to_tokens(const float* __restrict__ fused, float* __restrict__ jt)
{
  __shared__ float tile[32][33];
  int hw0 = blockIdx.x * 32, c0 = blockIdx.y * 32, b = blockIdx.z;
  #pragma unroll
  for (int i = 0; i < 4; ++i) {
    int c = c0 + threadIdx.y + i * 8;
    tile[threadIdx.y + i * 8][threadIdx.x] = fused[((size_t)b * CH + c) * HWP + hw0 + threadIdx.x];
  }
  __syncthreads();
  #pragma unroll
  for (int i = 0; i < 4; ++i) {
    int hw = hw0 + threadIdx.y + i * 8;
    jt[((size_t)(b * NTOK + NPRM + hw)) * CH + c0 + threadIdx.x] = tile[threadIdx.x][threadIdx.y + i * 8];
  }
}

// ---------------- enh: out[b,c,hw] = jt[b,8+hw,c] ----------------
__global__ __launch_bounds__(256) void tokens_to_img(const float* __restrict__ jt, float* __restrict__ out)
{
  __shared__ float tile[32][33];
  int hw0 = blockIdx.x * 32, c0 = blockIdx.y * 32, b = blockIdx.z;
  #pragma unroll
  for (int i = 0; i < 4; ++i) {
    int hw = hw0 + threadIdx.y + i * 8;
    tile[threadIdx.y + i * 8][threadIdx.x] = jt[((size_t)(b * NTOK + NPRM + hw)) * CH + c0 + threadIdx.x];
  }
  __syncthreads();
  #pragma unroll
  for (int i = 0; i < 4; ++i) {
    int c = c0 + threadIdx.y + i * 8;
    out[((size_t)b * CH + c) * HWP + hw0 + threadIdx.x] = tile[threadIdx.x][threadIdx.y + i * 8];
  }
}

// ---------------- row LayerNorm over 512 ----------------
__global__ __launch_bounds__(128) void ln_rows(
    const float* __restrict__ in, const float* __restrict__ lnp, float* __restrict__ out)
{
  int row = blockIdx.x;
  float4 val = ((const float4*)(in + (size_t)row * CH))[threadIdx.x];
  float sum = val.x + val.y + val.z + val.w;
  float sq = val.x * val.x + val.y * val.y + val.z * val.z + val.w * val.w;
  #pragma unroll
  for (int off = 1; off < 64; off <<= 1) { sum += __shfl_xor(sum, off); sq += __shfl_xor(sq, off); }
  __shared__ float s2[4];
  if ((threadIdx.x & 63) == 0) { s2[(threadIdx.x >> 6) * 2] = sum; s2[(threadIdx.x >> 6) * 2 + 1] = sq; }
  __syncthreads();
  sum = s2[0] + s2[2]; sq = s2[1] + s2[3];
  float mu = sum * (1.0f / 512.0f);
  float var = sq * (1.0f / 512.0f) - mu * mu;
  float rstd = rsqrtf(var + EPSV);
  int c = threadIdx.x * 4;
  float4 o;
  o.x = (val.x - mu) * rstd * lnp[c] + lnp[CH + c];
  o.y = (val.y - mu) * rstd * lnp[c + 1] + lnp[CH + c + 1];
  o.z = (val.z - mu) * rstd * lnp[c + 2] + lnp[CH + c + 2];
  o.w = (val.w - mu) * rstd * lnp[c + 3] + lnp[CH + c + 3];
  ((float4*)(out + (size_t)row * CH))[threadIdx.x] = o;
}

// ---------------- NT GEMM: Co[m,n] = epi(sum_k A[m,k]*Bw[n,k]) ----------------
__global__ __launch_bounds__(256) void gemm_nt(
    const float* __restrict__ A, const float* __restrict__ Bw,
    float* Co, const float* __restrict__ bias,
    const float* res, int M, int Nn, int K, int act)
{
  __shared__ __align__(16) float As[32][64];
  __shared__ __align__(16) float Bs[32][64];
  int t = threadIdx.x;
  int tx = t & 15, ty = t >> 4;
  int m0 = blockIdx.y * 64, n0 = blockIdx.x * 64;
  float acc[4][4] = {};
  for (int k0 = 0; k0 < K; k0 += 32) {
    __syncthreads();
    #pragma unroll
    for (int L = 0; L < 2; ++L) {
      int idx = t + 256 * L;
      int r = idx >> 3;
      int kc = (idx & 7) << 2;
      int gm = m0 + r;
      float4 va = (gm < M) ? *(const float4*)&A[(size_t)gm * K + k0 + kc] : make_float4(0.f, 0.f, 0.f, 0.f);
      As[kc + 0][r] = va.x; As[kc + 1][r] = va.y; As[kc + 2][r] = va.z; As[kc + 3][r] = va.w;
      float4 vb = *(const float4*)&Bw[(size_t)(n0 + r) * K + k0 + kc];
      Bs[kc + 0][r] = vb.x; Bs[kc + 1][r] = vb.y; Bs[kc + 2][r] = vb.z; Bs[kc + 3][r] = vb.w;
    }
    __syncthreads();
    #pragma unroll
    for (int kk = 0; kk < 32; ++kk) {
      float4 a4 = *(const float4*)&As[kk][ty * 4];
      float4 b4 = *(const float4*)&Bs[kk][tx * 4];
      acc[0][0] += a4.x * b4.x; acc[0][1] += a4.x * b4.y; acc[0][2] += a4.x * b4.z; acc[0][3] += a4.x * b4.w;
      acc[1][0] += a4.y * b4.x; acc[1][1] += a4.y * b4.y; acc[1][2] += a4.y * b4.z; acc[1][3] += a4.y * b4.w;
      acc[2][0] += a4.z * b4.x; acc[2][1] += a4.z * b4.y; acc[2][2] += a4.z * b4.z; acc[2][3] += a4.z * b4.w;
      acc[3][0] += a4.w * b4.x; acc[3][1] += a4.w * b4.y; acc[3][2] += a4.w * b4.z; acc[3][3] += a4.w * b4.w;
    }
  }
  #pragma unroll
  for (int i = 0; i < 4; ++i) {
    int m = m0 + ty * 4 + i;
    if (m >= M) break;
    #pragma unroll
    for (int j = 0; j < 4; ++j) {
      int n = n0 + tx * 4 + j;
      float vv = acc[i][j];
      if (bias) vv += bias[n];
      if (act) vv = gelu_f(vv);
      if (res) vv += res[(size_t)m * Nn + n];
      Co[(size_t)m * Nn + n] = vv;
    }
  }
}

// ---------------- flash attention fp32, geometry bias on the fly ----------------
__device__ __forceinline__ void tok_coord(int idx, float& y, float& x)
{
  if (idx < NPRM) { y = (float)(idx >> 2); x = (float)(idx & 3) * (1.0f / 3.0f); }
  else { int t = idx - NPRM; y = (float)(t >> 5) * (1.0f / 31.0f); x = (float)(t & 31) * (1.0f / 31.0f); }
}

__global__ __launch_bounds__(256) void attn_kernel(
    const float* __restrict__ q, const float* __restrict__ k,
    const float* __restrict__ v, const float* __restrict__ jd,
    const float* __restrict__ gw, float* __restrict__ ao)
{
  __shared__ __align__(16) float qs[16][64];
  __shared__ __align__(16) float ks[64][68];
  __shared__ __align__(16) float vs[64][68];
  __shared__ float ps[16][64];
  __shared__ float jdi[16];
  __shared__ float jdj[64];

  const int t = threadIdx.x;
  const int jj = t & 63;
  const int wv = t >> 6;
  const int i0 = blockIdx.x * 16;
  const int h = blockIdx.y;
  const int b = blockIdx.z;

  const float decay = logf(1.0f - exp2f(-1.0f - 0.5f * (float)h));
  const float g0 = gw[0] * decay;
  const float g1 = gw[1] * decay;

  #pragma unroll
  for (int a = 0; a < 4; ++a) {
    int idx = t + 256 * a;
    int r = idx >> 6, d = idx & 63;
    int gi = i0 + r;
    qs[r][d] = (gi < NTOK) ? q[((size_t)(b * NTOK + gi)) * CH + h * HD + d] * 0.125f : 0.0f;
  }
  if (t < 16) jdi[t] = (i0 + t < NTOK) ? jd[b * NTOK + i0 + t] : 0.0f;
  __syncthreads();

  float yi[4], xi[4], jdiv[4];
  #pragma unroll
  for (int kk = 0; kk < 4; ++kk) {
    int r = wv + 4 * kk;
    int gi = i0 + r; if (gi >= NTOK) gi = NTOK - 1;
    tok_coord(gi, yi[kk], xi[kk]);
    jdiv[kk] = jdi[r];
  }

  float m_r[4] = { -1e30f, -1e30f, -1e30f, -1e30f };
  float l_r[4] = { 0.f, 0.f, 0.f, 0.f };
  float o_acc[4] = { 0.f, 0.f, 0.f, 0.f };

  for (int j0 = 0; j0 < NTOK; j0 += 64) {
    __syncthreads();
    #pragma unroll
    for (int a = 0; a < 4; ++a) {
      int idx = t + 256 * a;
      int r = idx >> 4;
      int dc = (idx & 15) << 2;
      int gj = j0 + r;
      if (gj < NTOK) {
        *(float4*)&ks[r][dc] = *(const float4*)&k[((size_t)(b * NTOK + gj)) * CH + h * HD + dc];
        *(float4*)&vs[r][dc] = *(const float4*)&v[((size_t)(b * NTOK + gj)) * CH + h * HD + dc];
      } else {
        float4 z = make_float4(0.f, 0.f, 0.f, 0.f);
        *(float4*)&ks[r][dc] = z;
        *(float4*)&vs[r][dc] = z;
      }
    }
    if (t < 64) jdj[t] = (j0 + t < NTOK) ? jd[b * NTOK + j0 + t] : 0.0f;
    __syncthreads();

    int gj = j0 + jj;
    bool jval = gj < NTOK;
    float yj, xj;
    tok_coord(jval ? gj : NTOK - 1, yj, xj);
    float jdjv = jdj[jj];

    float sv[4] = { 0.f, 0.f, 0.f, 0.f };
    #pragma unroll
    for (int d = 0; d < 64; d += 4) {
      float4 kv = *(const float4*)&ks[jj][d];
      float4 q0 = *(const float4*)&qs[wv][d];
      float4 q1 = *(const float4*)&qs[wv + 4][d];
      float4 q2 = *(const float4*)&qs[wv + 8][d];
      float4 q3 = *(const float4*)&qs[wv + 12][d];
      sv[0] += q0.x * kv.x + q0.y * kv.y + q0.z * kv.z + q0.w * kv.w;
      sv[1] += q1.x * kv.x + q1.y * kv.y + q1.z * kv.z + q1.w * kv.w;
      sv[2] += q2.x * kv.x + q2.y * kv.y + q2.z * kv.z + q2.w * kv.w;
      sv[3] += q3.x * kv.x + q3.y * kv.y + q3.z * kv.z + q3.w * kv.w;
    }
    #pragma unroll
    for (int kk = 0; kk < 4; ++kk) {
      float bias = g0 * (fabsf(yi[kk] - yj) + fabsf(xi[kk] - xj)) + g1 * fabsf(jdiv[kk] - jdjv);
      sv[kk] = jval ? (sv[kk] + bias) : -1e30f;
    }
    float alpha[4];
    #pragma unroll
    for (int kk = 0; kk < 4; ++kk) {
      float mx = sv[kk];
      #pragma unroll
      for (int off = 1; off < 64; off <<= 1) mx = fmaxf(mx, __shfl_xor(mx, off));
      float mnew = fmaxf(m_r[kk], mx);
      alpha[kk] = expf(m_r[kk] - mnew);
      float p = expf(sv[kk] - mnew);
      float ssum = p;
      #pragma unroll
      for (int off = 1; off < 64; off <<= 1) ssum += __shfl_xor(ssum, off);
      l_r[kk] = l_r[kk] * alpha[kk] + ssum;
      m_r[kk] = mnew;
      ps[wv + 4 * kk][jj] = p;
    }
    __syncthreads();
    #pragma unroll
    for (int kk = 0; kk < 4; ++kk) o_acc[kk] *= alpha[kk];
    for (int jx = 0; jx < 64; ++jx) {
      float vvv = vs[jx][jj];
      o_acc[0] += ps[wv][jx] * vvv;
      o_acc[1] += ps[wv + 4][jx] * vvv;
      o_acc[2] += ps[wv + 8][jx] * vvv;
      o_acc[3] += ps[wv + 12][jx] * vvv;
    }
  }
  #pragma unroll
  for (int kk = 0; kk < 4; ++kk) {
    int gi = i0 + wv + 4 * kk;
    if (gi < NTOK) ao[((size_t)(b * NTOK + gi)) * CH + h * HD + jj] = o_acc[kk] / l_r[kk];
  }
}

// ---------------- host ----------------
extern "C" void kernel_launch(void* const* d_in, const int* in_sizes, int n_in,
                              void* d_out, int out_size, void* d_ws, size_t ws_size,
                              hipStream_t stream)
{
  const float* fused = (const float*)d_in[0];
  const float* depth = (const float*)d_in[1];
  const float* pg_dw_w = (const float*)d_in[2];
  const float* pg_bn1 = (const float*)d_in[3];
  const float* pg_pw_w = (const float*)d_in[4];
  const float* pg_bn2 = (const float*)d_in[5];
  const float* prompt_embed = (const float*)d_in[6];
  const float* pg_ln = (const float*)d_in[7];
  const float* gp_dw_w = (const float*)d_in[8];
  const float* gp_bn = (const float*)d_in[9];
  const float* gp_pw_w = (const float*)d_in[10];
  const float* gp_pw_b = (const float*)d_in[11];
  const float* gp_weight = (const float*)d_in[12];
  const float* ln1 = (const float*)d_in[13];
  const float* wq = (const float*)d_in[14];
  const float* wk = (const float*)d_in[15];
  const float* wv = (const float*)d_in[16];
  const float* wo = (const float*)d_in[17];
  const float* ln2 = (const float*)d_in[18];
  const float* mlp_w1 = (const float*)d_in[19];
  const float* mlp_b1 = (const float*)d_in[20];
  const float* mlp_w2 = (const float*)d_in[21];
  const float* mlp_b2 = (const float*)d_in[22];
  const float* op_dw_w = (const float*)d_in[23];
  const float* op_bn1 = (const float*)d_in[24];
  const float* op_pw_w = (const float*)d_in[25];
  const float* op_bn2 = (const float*)d_in[26];
  float* out = (float*)d_out;

  float* ws = (float*)d_ws;
  const size_t SZ_IMG = (size_t)BB * CH * HWP;       // 2,097,152
  const size_t SZ_TOK = (size_t)BB * NTOK * CH;      // 2,113,536
  float* Abuf = ws;
  float* Bf   = ws + SZ_IMG;
  float* jt   = ws + 2 * SZ_IMG;
  float* xb   = jt + SZ_TOK;
  float* qb   = xb + SZ_TOK;
  float* kb   = qb + SZ_TOK;
  float* vb   = kb + SZ_TOK;
  float* aob  = vb + SZ_TOK;
  float* hb   = aob + SZ_TOK;
  float* jd   = hb + (size_t)BB * NTOK * 1024;
  float* ppool = jd + BB * NTOK;

  // --- DepthPromptGenerator ---
  hipLaunchKernelGGL(dw_bn_gelu, dim3(BB * CH), dim3(256), 0, stream, depth, pg_dw_w, pg_bn1, Abuf);
  hipLaunchKernelGGL(pw_gemm, dim3(16, 8, BB), dim3(256), 0, stream, pg_pw_w, Abuf, Bf, pg_bn2, (const float*)nullptr, 0);
  hipLaunchKernelGGL(pp_pool, dim3(BB * CH), dim3(128), 0, stream, Bf, ppool);
  hipLaunchKernelGGL(prompt_ln, dim3(BB * NPRM), dim3(128), 0, stream, ppool, prompt_embed, pg_ln, jt);

  // --- GeometryPriorGenerator ---
  hipLaunchKernelGGL(dw_bn_gelu, dim3(BB * CH), dim3(256), 0, stream, depth, gp_dw_w, gp_bn, Abuf);
  hipLaunchKernelGGL(gp_pw, dim3(4, BB), dim3(256), 0, stream, Abuf, gp_pw_w, gp_pw_b, jd);
  hipLaunchKernelGGL(jd_pool, dim3(BB), dim3(256), 0, stream, jd);

  // --- Mixer: build jt, LN, QKV ---
  hipLaunchKernelGGL(img_to_tokens, dim3(32, 16, BB), dim3(32, 8), 0, stream, fused, jt);
  hipLaunchKernelGGL(ln_rows, dim3(BB * NTOK), dim3(128), 0, stream, jt, ln1, xb);
  hipLaunchKernelGGL(gemm_nt, dim3(8, 65), dim3(256), 0, stream, xb, wq, qb, (const float*)nullptr, (const float*)nullptr, BB * NTOK, CH, CH, 0);
  hipLaunchKernelGGL(gemm_nt, dim3(8, 65), dim3(256), 0, stream, xb, wk, kb, (const float*)nullptr, (const float*)nullptr, BB * NTOK, CH, CH, 0);
  hipLaunchKernelGGL(gemm_nt, dim3(8, 65), dim3(256), 0, stream, xb, wv, vb, (const float*)nullptr, (const float*)nullptr, BB * NTOK, CH, CH, 0);

  hipLaunchKernelGGL(attn_kernel, dim3(65, 8, BB), dim3(256), 0, stream, qb, kb, vb, jd, gp_weight, aob);

  hipLaunchKernelGGL(gemm_nt, dim3(8, 65), dim3(256), 0, stream, aob, wo, jt, (const float*)nullptr, jt, BB * NTOK, CH, CH, 0);
  hipLaunchKernelGGL(ln_rows, dim3(BB * NTOK), dim3(128), 0, stream, jt, ln2, xb);
  hipLaunchKernelGGL(gemm_nt, dim3(16, 65), dim3(256), 0, stream, xb, mlp_w1, hb, mlp_b1, (const float*)nullptr, BB * NTOK, 1024, CH, 1);
  hipLaunchKernelGGL(gemm_nt, dim3(8, 65), dim3(256), 0, stream, hb, mlp_w2, jt, mlp_b2, jt, BB * NTOK, CH, 1024, 0);

  // --- out_proj ---
  hipLaunchKernelGGL(tokens_to_img, dim3(32, 16, BB), dim3(32, 8), 0, stream, jt, Bf);
  hipLaunchKernelGGL(dw_bn_gelu, dim3(BB * CH), dim3(256), 0, stream, Bf, op_dw_w, op_bn1, Abuf);
  hipLaunchKernelGGL(pw_gemm, dim3(16, 8, BB), dim3(256), 0, stream, op_pw_w, Abuf, out, op_bn2, fused, 1);
}

// Round 2
// 469.064 us; speedup vs baseline: 2.3279x; 2.3279x over previous
//
#include <hip/hip_runtime.h>
#include <math.h>

typedef __attribute__((ext_vector_type(8))) short bf16x8;
typedef __attribute__((ext_vector_type(4))) float f32x4;

#define CH 512
#define HWP 1024
#define NTOK 1032
#define NTP 1088
#define NPRM 8
#define BB 4
#define EPSV 1e-5f
#define MTOK 4128
#define MPAD 4224

__device__ __forceinline__ float gelu_f(float x) {
  return 0.5f * x * (1.0f + erff(x * 0.70710678118654752440f));
}

__device__ __forceinline__ ushort f2bf(float x) {
  union { float f; unsigned u; } v; v.f = x;
  unsigned r = v.u + 0x7FFF + ((v.u >> 16) & 1);
  return (ushort)(r >> 16);
}

// ---------------- weight fp32 -> bf16 conversion (packed arena) ----------------
// layout: wq|wk|wv (786432) | wo (262144) | w1 (524288) | w2 (524288) | pgw (262144) | opw (262144)
__global__ __launch_bounds__(256) void convw(
    const float* __restrict__ wq, const float* __restrict__ wk, const float* __restrict__ wv,
    const float* __restrict__ wo, const float* __restrict__ w1, const float* __restrict__ w2,
    const float* __restrict__ pgw, const float* __restrict__ opw, ushort* __restrict__ out)
{
  const int total = 2621440;
  for (int i = blockIdx.x * 256 + threadIdx.x; i < total; i += gridDim.x * 256) {
    const float* src; int off;
    if (i < 262144)       { src = wq;  off = i; }
    else if (i < 524288)  { src = wk;  off = i - 262144; }
    else if (i < 786432)  { src = wv;  off = i - 524288; }
    else if (i < 1048576) { src = wo;  off = i - 786432; }
    else if (i < 1572864) { src = w1;  off = i - 1048576; }
    else if (i < 2097152) { src = w2;  off = i - 1572864; }
    else if (i < 2359296) { src = pgw; off = i - 2097152; }
    else                  { src = opw; off = i - 2359296; }
    out[i] = f2bf(src[off]);
  }
}

// ---------------- depthwise 3x3 + BN + GELU (fp32, [b][c][hw]) ----------------
__global__ __launch_bounds__(256) void dw_bn_gelu(
    const float* __restrict__ in, const float* __restrict__ w,
    const float* __restrict__ bn, float* __restrict__ out)
{
  int bc = blockIdx.x;
  int c = bc & (CH - 1);
  float w9[9];
  #pragma unroll
  for (int i = 0; i < 9; ++i) w9[i] = w[c * 9 + i];
  float g = bn[c], be = bn[CH + c], mm = bn[2 * CH + c], vv = bn[3 * CH + c];
  float s = g * rsqrtf(vv + EPSV);
  float sh = be - mm * s;
  const float* ip = in + (size_t)bc * HWP;
  float* op = out + (size_t)bc * HWP;
  for (int px = threadIdx.x; px < HWP; px += 256) {
    int y = px >> 5, x = px & 31;
    float acc = 0.0f;
    #pragma unroll
    for (int dy = 0; dy < 3; ++dy) {
      int yy = y + dy - 1;
      if ((unsigned)yy < 32u) {
        #pragma unroll
        for (int dx = 0; dx < 3; ++dx) {
          int xx = x + dx - 1;
          if ((unsigned)xx < 32u) acc += ip[yy * 32 + xx] * w9[dy * 3 + dx];
        }
      }
    }
    op[px] = gelu_f(acc * s + sh);
  }
}

// ---------------- [b][c][hw] f32 -> [b*hw][c] bf16 transpose ----------------
__global__ __launch_bounds__(256) void c2t(const float* __restrict__ in, ushort* __restrict__ out)
{
  __shared__ float tile[32][33];
  int hw0 = blockIdx.x * 32, c0 = blockIdx.y * 32, b = blockIdx.z;
  int tx = threadIdx.x, ty = threadIdx.y;
  #pragma unroll
  for (int i = 0; i < 4; ++i)
    tile[ty + i * 8][tx] = in[((size_t)(b * CH + c0 + ty + i * 8)) * HWP + hw0 + tx];
  __syncthreads();
  #pragma unroll
  for (int i = 0; i < 4; ++i)
    out[((size_t)(b * HWP + hw0 + ty + i * 8)) * CH + c0 + tx] = f2bf(tile[tx][ty + i * 8]);
}

// ---------------- GEMM core: 128x128 tile, NT, bf16 MFMA ----------------
__device__ __forceinline__ void gemm_core(
    const ushort* __restrict__ A, const ushort* __restrict__ B,
    int m0, int n0, int K, short* sA, short* sB, f32x4 (&acc)[4][4])
{
  const int t = threadIdx.x;
  const int l = t & 63, w = t >> 6;
  const int wm = (w >> 1) * 64, wn = (w & 1) * 64;
  const int srow = t >> 2, skb = t & 3;
  for (int k0 = 0; k0 < K; k0 += 32) {
    int4 va0 = *(const int4*)(A + (size_t)(m0 + srow) * K + k0 + skb * 8);
    int4 va1 = *(const int4*)(A + (size_t)(m0 + 64 + srow) * K + k0 + skb * 8);
    int4 vb0 = *(const int4*)(B + (size_t)(n0 + srow) * K + k0 + skb * 8);
    int4 vb1 = *(const int4*)(B + (size_t)(n0 + 64 + srow) * K + k0 + skb * 8);
    *(int4*)(sA + (skb * 128 + srow) * 8) = va0;
    *(int4*)(sA + (skb * 128 + 64 + srow) * 8) = va1;
    *(int4*)(sB + (skb * 128 + srow) * 8) = vb0;
    *(int4*)(sB + (skb * 128 + 64 + srow) * 8) = vb1;
    __syncthreads();
    bf16x8 af[4], bfr[4];
    #pragma unroll
    for (int mf = 0; mf < 4; ++mf)
      af[mf] = *(const bf16x8*)(sA + ((l >> 4) * 128 + wm + mf * 16 + (l & 15)) * 8);
    #pragma unroll
    for (int nf = 0; nf < 4; ++nf)
      bfr[nf] = *(const bf16x8*)(sB + ((l >> 4) * 128 + wn + nf * 16 + (l & 15)) * 8);
    #pragma unroll
    for (int mf = 0; mf < 4; ++mf) {
      #pragma unroll
      for (int nf = 0; nf < 4; ++nf)
        acc[mf][nf] = __builtin_amdgcn_mfma_f32_16x16x32_bf16(af[mf], bfr[nf], acc[mf][nf], 0, 0, 0);
    }
    __syncthreads();
  }
}

#define GEMM_PRE \
  __shared__ short sA[4096], sB[4096]; \
  f32x4 acc[4][4]; \
  { f32x4 z = {0.f, 0.f, 0.f, 0.f}; \
    _Pragma("unroll") for (int i = 0; i < 4; ++i) { _Pragma("unroll") for (int j = 0; j < 4; ++j) acc[i][j] = z; } } \
  const int n0 = blockIdx.x * 128, m0 = blockIdx.y * 128; \
  const int t = threadIdx.x, l = t & 63, w = t >> 6; \
  const int wm = (w >> 1) * 64, wn = (w & 1) * 64;

// QKV fused: N=1536 -> q/k/v in [b][h][tok(1088)][64] bf16
__global__ __launch_bounds__(256) void gemm_qkv(
    const ushort* __restrict__ A, const ushort* __restrict__ B,
    ushort* __restrict__ qh, ushort* __restrict__ kh, ushort* __restrict__ vh)
{
  GEMM_PRE
  gemm_core(A, B, m0, n0, CH, sA, sB, acc);
  #pragma unroll
  for (int nf = 0; nf < 4; ++nf) {
    int n = n0 + wn + nf * 16 + (l & 15);
    ushort* dst = (n < 512) ? qh : (n < 1024 ? kh : vh);
    int np = n & 511;
    int h = np >> 6, d = np & 63;
    #pragma unroll
    for (int mf = 0; mf < 4; ++mf) {
      #pragma unroll
      for (int r = 0; r < 4; ++r) {
        int m = m0 + wm + mf * 16 + (l >> 4) * 4 + r;
        if (m < MTOK) {
          int b = m / NTOK;
          int tok = m - b * NTOK;
          dst[((size_t)((b * 8 + h) * NTP) + tok) * 64 + d] = f2bf(acc[mf][nf][r]);
        }
      }
    }
  }
}

// residual f32 accumulate: Cf[m*512+n] += acc + bias (wo, mlp2)
__global__ __launch_bounds__(256) void gemm_res(
    const ushort* __restrict__ A, const ushort* __restrict__ B,
    float* __restrict__ Cf, const float* __restrict__ bias, int K)
{
  GEMM_PRE
  gemm_core(A, B, m0, n0, K, sA, sB, acc);
  #pragma unroll
  for (int nf = 0; nf < 4; ++nf) {
    int n = n0 + wn + nf * 16 + (l & 15);
    float bv = bias ? bias[n] : 0.0f;
    #pragma unroll
    for (int mf = 0; mf < 4; ++mf) {
      #pragma unroll
      for (int r = 0; r < 4; ++r) {
        int m = m0 + wm + mf * 16 + (l >> 4) * 4 + r;
        if (m < MTOK) {
          size_t idx = (size_t)m * 512 + n;
          Cf[idx] += acc[mf][nf][r] + bv;
        }
      }
    }
  }
}

// mlp1: bias + gelu -> bf16 [m][1024]
__global__ __launch_bounds__(256) void gemm_gelu_bf(
    const ushort* __restrict__ A, const ushort* __restrict__ B,
    const float* __restrict__ bias, ushort* __restrict__ Ob)
{
  GEMM_PRE
  gemm_core(A, B, m0, n0, CH, sA, sB, acc);
  #pragma unroll
  for (int nf = 0; nf < 4; ++nf) {
    int n = n0 + wn + nf * 16 + (l & 15);
    float bv = bias[n];
    #pragma unroll
    for (int mf = 0; mf < 4; ++mf) {
      #pragma unroll
      for (int r = 0; r < 4; ++r) {
        int m = m0 + wm + mf * 16 + (l >> 4) * 4 + r;
        if (m < MTOK) Ob[(size_t)m * 1024 + n] = f2bf(gelu_f(acc[mf][nf][r] + bv));
      }
    }
  }
}

// pointwise conv GEMM: A=[b*hw][c] bf16, B=W[o][c] bf16; out f32 [b][o][hw] via frag transpose.
// MODE 0: BN+GELU.  MODE 1: BN + res add.
template<int MODE>
__global__ __launch_bounds__(256) void gemm_pw(
    const ushort* __restrict__ A, const ushort* __restrict__ B,
    const float* __restrict__ bn, const float* __restrict__ res, float* __restrict__ Of)
{
  __shared__ float patch[4][16][20];
  GEMM_PRE
  gemm_core(A, B, m0, n0, CH, sA, sB, acc);
  #pragma unroll
  for (int nf = 0; nf < 4; ++nf) {
    int o = n0 + wn + nf * 16 + (l & 15);
    float g = bn[o], be = bn[CH + o], mm = bn[2 * CH + o], vv = bn[3 * CH + o];
    float s = g * rsqrtf(vv + EPSV);
    float sh = be - mm * s;
    #pragma unroll
    for (int mf = 0; mf < 4; ++mf) {
      #pragma unroll
      for (int r = 0; r < 4; ++r) {
        float x = acc[mf][nf][r] * s + sh;
        if (MODE == 0) x = gelu_f(x);
        patch[w][(l >> 4) * 4 + r][l & 15] = x;
      }
      asm volatile("s_waitcnt lgkmcnt(0)" ::: "memory");
      f32x4 tv = *(const f32x4*)&patch[w][l & 15][(l >> 4) * 4];
      int m = m0 + wm + mf * 16 + (l & 15);
      int b = m >> 10, hw = m & 1023;
      #pragma unroll
      for (int r = 0; r < 4; ++r) {
        int o2 = n0 + wn + nf * 16 + (l >> 4) * 4 + r;
        size_t oidx = ((size_t)(b * CH + o2)) * HWP + hw;
        float x = tv[r];
        if (MODE == 1) x += res[oidx];
        Of[oidx] = x;
      }
      asm volatile("s_waitcnt lgkmcnt(0)" ::: "memory");
    }
  }
}

// ---------------- pp pooling (input [b][c][hw] f32) ----------------
__global__ __launch_bounds__(128) void pp_pool(const float* __restrict__ pp, float* __restrict__ ppool)
{
  int bc = blockIdx.x;
  int b = bc >> 9, c = bc & 511;
  __shared__ float sums[8];
  if (threadIdx.x < 8) sums[threadIdx.x] = 0.0f;
  __syncthreads();
  const float* ip = pp + (size_t)bc * HWP;
  float s0 = 0.0f, s1 = 0.0f;
  #pragma unroll
  for (int kq = 0; kq < 8; ++kq) {
    float val = ip[threadIdx.x + kq * 128];
    if (kq < 4) s0 += val; else s1 += val;
  }
  int pxr = (threadIdx.x & 31) >> 3;
  atomicAdd(&sums[pxr], s0);
  atomicAdd(&sums[4 + pxr], s1);
  __syncthreads();
  if (threadIdx.x < 8)
    ppool[((size_t)b * 8 + threadIdx.x) * CH + c] = sums[threadIdx.x] * (1.0f / 128.0f);
}

// ---------------- prompt: + embed, LayerNorm -> jt rows ----------------
__global__ __launch_bounds__(128) void prompt_ln(
    const float* __restrict__ ppool, const float* __restrict__ embed,
    const float* __restrict__ lnp, float* __restrict__ jt)
{
  int rB = blockIdx.x;
  int b = rB >> 3, pI = rB & 7;
  float4 val = ((const float4*)(ppool + (size_t)rB * CH))[threadIdx.x];
  float4 e = ((const float4*)(embed + (size_t)pI * CH))[threadIdx.x];
  val.x += e.x; val.y += e.y; val.z += e.z; val.w += e.w;
  float sum = val.x + val.y + val.z + val.w;
  float sq = val.x * val.x + val.y * val.y + val.z * val.z + val.w * val.w;
  #pragma unroll
  for (int off = 1; off < 64; off <<= 1) { sum += __shfl_xor(sum, off); sq += __shfl_xor(sq, off); }
  __shared__ float s2[4];
  if ((threadIdx.x & 63) == 0) { s2[(threadIdx.x >> 6) * 2] = sum; s2[(threadIdx.x >> 6) * 2 + 1] = sq; }
  __syncthreads();
  sum = s2[0] + s2[2]; sq = s2[1] + s2[3];
  float mu = sum * (1.0f / 512.0f);
  float var = sq * (1.0f / 512.0f) - mu * mu;
  float rstd = rsqrtf(var + EPSV);
  int c = threadIdx.x * 4;
  float4 o;
  o.x = (val.x - mu) * rstd * lnp[c] + lnp[CH + c];
  o.y = (val.y - mu) * rstd * lnp[c + 1] + lnp[CH + c + 1];
  o.z = (val.z - mu) * rstd * lnp[c + 2] + lnp[CH + c + 2];
  o.w = (val.w - mu) * rstd * lnp[c + 3] + lnp[CH + c + 3];
  ((float4*)(jt + ((size_t)(b * NTOK + pI)) * CH))[threadIdx.x] = o;
}

// ---------------- gp pointwise (C->1) -> jd image part ----------------
__global__ __launch_bounds__(256) void gp_pw(
    const float* __restrict__ in, const float* __restrict__ w,
    const float* __restrict__ b0, float* __restrict__ jd)
{
  int b = blockIdx.y;
  int hw = blockIdx.x * 256 + threadIdx.x;
  __shared__ float wsm[CH];
  wsm[threadIdx.x] = w[threadIdx.x];
  wsm[256 + threadIdx.x] = w[256 + threadIdx.x];
  __syncthreads();
  const float* ip = in + (size_t)b * CH * HWP + hw;
  float acc = 0.0f;
  for (int c = 0; c < CH; ++c) acc += wsm[c] * ip[(size_t)c * HWP];
  jd[b * NTP + NPRM + hw] = acc + b0[0];
}

__global__ __launch_bounds__(256) void jd_pool(float* jd)
{
  int b = blockIdx.x;
  __shared__ float sums[8];
  if (threadIdx.x < 8) sums[threadIdx.x] = 0.0f;
  __syncthreads();
  #pragma unroll
  for (int kq = 0; kq < 4; ++kq) {
    int px = threadIdx.x + kq * 256;
    int y = px >> 5, x = px & 31;
    int r = (y >> 4) * 4 + (x >> 3);
    atomicAdd(&sums[r], jd[b * NTP + NPRM + px]);
  }
  __syncthreads();
  if (threadIdx.x < 8) jd[b * NTP + threadIdx.x] = sums[threadIdx.x] * (1.0f / 128.0f);
}

// ---------------- img tokens: jt[b,8+hw,c] = fused[b,c,hw] ----------------
__global__ __launch_bounds__(256) void img_to_tokens(const float* __restrict__ fused, float* __restrict__ jt)
{
  __shared__ float tile[32][33];
  int hw0 = blockIdx.x * 32, c0 = blockIdx.y * 32, b = blockIdx.z;
  int tx = threadIdx.x, ty = threadIdx.y;
  #pragma unroll
  for (int i = 0; i < 4; ++i)
    tile[ty + i * 8][tx] = fused[((size_t)(b * CH + c0 + ty + i * 8)) * HWP + hw0 + tx];
  __syncthreads();
  #pragma unroll
  for (int i = 0; i < 4; ++i)
    jt[((size_t)(b * NTOK + NPRM + hw0 + ty + i * 8)) * CH + c0 + tx] = tile[tx][ty + i * 8];
}

__global__ __launch_bounds__(256) void tokens_to_img(const float* __restrict__ jt, float* __restrict__ out)
{
  __shared__ float tile[32][33];
  int hw0 = blockIdx.x * 32, c0 = blockIdx.y * 32, b = blockIdx.z;
  int tx = threadIdx.x, ty = threadIdx.y;
  #pragma unroll
  for (int i = 0; i < 4; ++i)
    tile[ty + i * 8][tx] = jt[((size_t)(b * NTOK + NPRM + hw0 + ty + i * 8)) * CH + c0 + tx];
  __syncthreads();
  #pragma unroll
  for (int i = 0; i < 4; ++i)
    out[((size_t)(b * CH + c0 + ty + i * 8)) * HWP + hw0 + tx] = tile[tx][ty + i * 8];
}

// ---------------- row LayerNorm -> bf16 ----------------
__global__ __launch_bounds__(128) void ln_rows_bf(
    const float* __restrict__ in, const float* __restrict__ lnp, ushort* __restrict__ out)
{
  int row = blockIdx.x;
  float4 val = ((const float4*)(in + (size_t)row * CH))[threadIdx.x];
  float sum = val.x + val.y + val.z + val.w;
  float sq = val.x * val.x + val.y * val.y + val.z * val.z + val.w * val.w;
  #pragma unroll
  for (int off = 1; off < 64; off <<= 1) { sum += __shfl_xor(sum, off); sq += __shfl_xor(sq, off); }
  __shared__ float s2[4];
  if ((threadIdx.x & 63) == 0) { s2[(threadIdx.x >> 6) * 2] = sum; s2[(threadIdx.x >> 6) * 2 + 1] = sq; }
  __syncthreads();
  sum = s2[0] + s2[2]; sq = s2[1] + s2[3];
  float mu = sum * (1.0f / 512.0f);
  float var = sq * (1.0f / 512.0f) - mu * mu;
  float rstd = rsqrtf(var + EPSV);
  int c = threadIdx.x * 4;
  ushort4 o;
  o.x = f2bf((val.x - mu) * rstd * lnp[c] + lnp[CH + c]);
  o.y = f2bf((val.y - mu) * rstd * lnp[c + 1] + lnp[CH + c + 1]);
  o.z = f2bf((val.z - mu) * rstd * lnp[c + 2] + lnp[CH + c + 2]);
  o.w = f2bf((val.w - mu) * rstd * lnp[c + 3] + lnp[CH + c + 3]);
  *(ushort4*)(out + (size_t)row * CH + c) = o;
}

// ---------------- V transpose: [bh][tok(1088)][64] -> [bh][64][tok(1088)] ----------------
__global__ __launch_bounds__(256) void transp_v(const ushort* __restrict__ vh, ushort* __restrict__ vT)
{
  __shared__ ushort tile[32][33];
  int tok0 = blockIdx.x * 32, d0 = blockIdx.y * 32;
  int bh = blockIdx.z;
  int tx = threadIdx.x, ty = threadIdx.y;
  #pragma unroll
  for (int i = 0; i < 4; ++i)
    tile[ty + i * 8][tx] = vh[((size_t)bh * NTP + tok0 + ty + i * 8) * 64 + d0 + tx];
  __syncthreads();
  #pragma unroll
  for (int i = 0; i < 4; ++i)
    vT[((size_t)bh * 64 + d0 + ty + i * 8) * NTP + tok0 + tx] = tile[tx][ty + i * 8];
}

// ---------------- MFMA flash attention ----------------
__device__ __forceinline__ void tok_coord(int idx, float& y, float& x)
{
  if (idx < NPRM) { y = (float)(idx >> 2); x = (float)(idx & 3) * (1.0f / 3.0f); }
  else { int t = idx - NPRM; y = (float)(t >> 5) * (1.0f / 31.0f); x = (float)(t & 31) * (1.0f / 31.0f); }
}

__global__ __launch_bounds__(64) void attn_mfma(
    const ushort* __restrict__ qh, const ushort* __restrict__ kh,
    const ushort* __restrict__ vT, const float* __restrict__ jd,
    const float* __restrict__ gw, ushort* __restrict__ ao)
{
  const int l = threadIdx.x;
  const int i0 = blockIdx.x * 16;
  const int h = blockIdx.y, b = blockIdx.z;
  const ushort* Q = qh + (size_t)(b * 8 + h) * NTP * 64;
  const ushort* K = kh + (size_t)(b * 8 + h) * NTP * 64;
  const ushort* V = vT + (size_t)(b * 8 + h) * 64 * NTP;
  const float decay = logf(1.0f - exp2f(-1.0f - 0.5f * (float)h));
  const float g0 = gw[0] * decay;
  const float g1 = gw[1] * decay;

  bf16x8 qf0 = *(const bf16x8*)(Q + (size_t)(i0 + (l & 15)) * 64 + (l >> 4) * 8);
  bf16x8 qf1 = *(const bf16x8*)(Q + (size_t)(i0 + (l & 15)) * 64 + 32 + (l >> 4) * 8);

  float yi[4], xi[4], jdi[4];
  #pragma unroll
  for (int r = 0; r < 4; ++r) {
    int i = i0 + (l >> 4) * 4 + r;
    tok_coord(i, yi[r], xi[r]);
    jdi[r] = jd[b * NTP + i];
  }

  float m_r[4] = { -1e30f, -1e30f, -1e30f, -1e30f };
  float l_r[4] = { 0.f, 0.f, 0.f, 0.f };
  f32x4 of[4];
  { f32x4 z = {0.f, 0.f, 0.f, 0.f};
    #pragma unroll
    for (int d = 0; d < 4; ++d) of[d] = z; }

  __shared__ ushort Pl[16][72];

  for (int j0 = 0; j0 < NTOK; j0 += 64) {
    f32x4 sfr[4];
    #pragma unroll
    for (int jf = 0; jf < 4; ++jf) {
      const ushort* kp = K + (size_t)(j0 + jf * 16 + (l & 15)) * 64 + (l >> 4) * 8;
      bf16x8 k0 = *(const bf16x8*)kp;
      bf16x8 k1 = *(const bf16x8*)(kp + 32);
      f32x4 z = {0.f, 0.f, 0.f, 0.f};
      z = __builtin_amdgcn_mfma_f32_16x16x32_bf16(qf0, k0, z, 0, 0, 0);
      z = __builtin_amdgcn_mfma_f32_16x16x32_bf16(qf1, k1, z, 0, 0, 0);
      sfr[jf] = z;
    }
    float pv[4][4];
    float mt[4] = { -1e30f, -1e30f, -1e30f, -1e30f };
    #pragma unroll
    for (int jf = 0; jf < 4; ++jf) {
      int jj = j0 + jf * 16 + (l & 15);
      float yj, xj;
      tok_coord(jj, yj, xj);
      float jdj = jd[b * NTP + jj];
      bool valid = jj < NTOK;
      #pragma unroll
      for (int r = 0; r < 4; ++r) {
        float bias = g0 * (fabsf(yi[r] - yj) + fabsf(xi[r] - xj)) + g1 * fabsf(jdi[r] - jdj);
        float sv = valid ? (sfr[jf][r] * 0.125f + bias) : -1e30f;
        pv[jf][r] = sv;
        mt[r] = fmaxf(mt[r], sv);
      }
    }
    #pragma unroll
    for (int r = 0; r < 4; ++r) {
      #pragma unroll
      for (int off = 1; off < 16; off <<= 1) mt[r] = fmaxf(mt[r], __shfl_xor(mt[r], off));
    }
    float alpha[4], ls[4];
    #pragma unroll
    for (int r = 0; r < 4; ++r) {
      float mn = fmaxf(m_r[r], mt[r]);
      alpha[r] = __expf(m_r[r] - mn);
      m_r[r] = mn;
      ls[r] = 0.f;
    }
    #pragma unroll
    for (int jf = 0; jf < 4; ++jf) {
      #pragma unroll
      for (int r = 0; r < 4; ++r) {
        float p = __expf(pv[jf][r] - m_r[r]);
        pv[jf][r] = p;
        ls[r] += p;
      }
    }
    #pragma unroll
    for (int r = 0; r < 4; ++r) {
      #pragma unroll
      for (int off = 1; off < 16; off <<= 1) ls[r] += __shfl_xor(ls[r], off);
      l_r[r] = l_r[r] * alpha[r] + ls[r];
    }
    #pragma unroll
    for (int d = 0; d < 4; ++d) {
      #pragma unroll
      for (int r = 0; r < 4; ++r) of[d][r] *= alpha[r];
    }
    #pragma unroll
    for (int jf = 0; jf < 4; ++jf) {
      #pragma unroll
      for (int r = 0; r < 4; ++r)
        Pl[(l >> 4) * 4 + r][jf * 16 + (l & 15)] = f2bf(pv[jf][r]);
    }
    asm volatile("s_waitcnt lgkmcnt(0)" ::: "memory");
    bf16x8 pa0 = *(const bf16x8*)&Pl[l & 15][(l >> 4) * 8];
    bf16x8 pa1 = *(const bf16x8*)&Pl[l & 15][32 + (l >> 4) * 8];
    #pragma unroll
    for (int df = 0; df < 4; ++df) {
      const ushort* vp = V + (size_t)(df * 16 + (l & 15)) * NTP + j0 + (l >> 4) * 8;
      bf16x8 v0 = *(const bf16x8*)vp;
      bf16x8 v1 = *(const bf16x8*)(vp + 32);
      of[df] = __builtin_amdgcn_mfma_f32_16x16x32_bf16(pa0, v0, of[df], 0, 0, 0);
      of[df] = __builtin_amdgcn_mfma_f32_16x16x32_bf16(pa1, v1, of[df], 0, 0, 0);
    }
    asm volatile("s_waitcnt lgkmcnt(0)" ::: "memory");
  }
  #pragma unroll
  for (int r = 0; r < 4; ++r) {
    int i = i0 + (l >> 4) * 4 + r;
    if (i < NTOK) {
      float inv = 1.0f / l_r[r];
      #pragma unroll
      for (int df = 0; df < 4; ++df)
        ao[((size_t)(b * NTOK + i)) * 512 + h * 64 + df * 16 + (l & 15)] = f2bf(of[df][r] * inv);
    }
  }
}

// ---------------- host ----------------
extern "C" void kernel_launch(void* const* d_in, const int* in_sizes, int n_in,
                              void* d_out, int out_size, void* d_ws, size_t ws_size,
                              hipStream_t stream)
{
  const float* fused = (const float*)d_in[0];
  const float* depth = (const float*)d_in[1];
  const float* pg_dw_w = (const float*)d_in[2];
  const float* pg_bn1 = (const float*)d_in[3];
  const float* pg_pw_w = (const float*)d_in[4];
  const float* pg_bn2 = (const float*)d_in[5];
  const float* prompt_embed = (const float*)d_in[6];
  const float* pg_ln = (const float*)d_in[7];
  const float* gp_dw_w = (const float*)d_in[8];
  const float* gp_bn = (const float*)d_in[9];
  const float* gp_pw_w = (const float*)d_in[10];
  const float* gp_pw_b = (const float*)d_in[11];
  const float* gp_weight = (const float*)d_in[12];
  const float* ln1 = (const float*)d_in[13];
  const float* wq = (const float*)d_in[14];
  const float* wk = (const float*)d_in[15];
  const float* wv = (const float*)d_in[16];
  const float* wo = (const float*)d_in[17];
  const float* ln2 = (const float*)d_in[18];
  const float* mlp_w1 = (const float*)d_in[19];
  const float* mlp_b1 = (const float*)d_in[20];
  const float* mlp_w2 = (const float*)d_in[21];
  const float* mlp_b2 = (const float*)d_in[22];
  const float* op_dw_w = (const float*)d_in[23];
  const float* op_bn1 = (const float*)d_in[24];
  const float* op_pw_w = (const float*)d_in[25];
  const float* op_bn2 = (const float*)d_in[26];
  float* out = (float*)d_out;

  char* p = (char*)d_ws;
  auto alloc = [&](size_t bytes) { char* r = p; p += (bytes + 1023) & ~(size_t)1023; return r; };
  float*  jt   = (float*) alloc((size_t)MTOK * 512 * 4);
  ushort* xb   = (ushort*)alloc((size_t)MPAD * 512 * 2);
  ushort* hb   = (ushort*)alloc((size_t)MPAD * 1024 * 2);
  ushort* ao   = (ushort*)alloc((size_t)MPAD * 512 * 2);
  ushort* qhB  = (ushort*)alloc((size_t)32 * NTP * 64 * 2);
  ushort* khB  = (ushort*)alloc((size_t)32 * NTP * 64 * 2);
  ushort* vhB  = (ushort*)alloc((size_t)32 * NTP * 64 * 2);
  ushort* vTB  = (ushort*)alloc((size_t)32 * NTP * 64 * 2);
  float*  dwA  = (float*) alloc((size_t)BB * CH * HWP * 4);
  ushort* dwT  = (ushort*)alloc((size_t)BB * HWP * CH * 2);
  float*  ppf  = (float*) alloc((size_t)BB * CH * HWP * 4);
  float*  Bf   = (float*) alloc((size_t)BB * CH * HWP * 4);
  float*  jdv  = (float*) alloc((size_t)BB * NTP * 4);
  float*  ppool= (float*) alloc((size_t)BB * 8 * CH * 4);
  ushort* wbf  = (ushort*)alloc((size_t)2621440 * 2);

  ushort* wqkv_bf = wbf;
  ushort* wo_bf   = wbf + 786432;
  ushort* w1_bf   = wbf + 1048576;
  ushort* w2_bf   = wbf + 1572864;
  ushort* pgw_bf  = wbf + 2097152;
  ushort* opw_bf  = wbf + 2359296;

  hipLaunchKernelGGL(convw, dim3(4096), dim3(256), 0, stream,
                     wq, wk, wv, wo, mlp_w1, mlp_w2, pg_pw_w, op_pw_w, wbf);

  // --- DepthPromptGenerator ---
  hipLaunchKernelGGL(dw_bn_gelu, dim3(BB * CH), dim3(256), 0, stream, depth, pg_dw_w, pg_bn1, dwA);
  hipLaunchKernelGGL(c2t, dim3(32, 16, BB), dim3(32, 8), 0, stream, dwA, dwT);
  hipLaunchKernelGGL(gemm_pw<0>, dim3(4, 32), dim3(256), 0, stream, dwT, pgw_bf, pg_bn2, (const float*)nullptr, ppf);
  hipLaunchKernelGGL(pp_pool, dim3(BB * CH), dim3(128), 0, stream, ppf, ppool);
  hipLaunchKernelGGL(prompt_ln, dim3(BB * NPRM), dim3(128), 0, stream, ppool, prompt_embed, pg_ln, jt);

  // --- GeometryPriorGenerator ---
  hipLaunchKernelGGL(dw_bn_gelu, dim3(BB * CH), dim3(256), 0, stream, depth, gp_dw_w, gp_bn, dwA);
  hipLaunchKernelGGL(gp_pw, dim3(4, BB), dim3(256), 0, stream, dwA, gp_pw_w, gp_pw_b, jdv);
  hipLaunchKernelGGL(jd_pool, dim3(BB), dim3(256), 0, stream, jdv);

  // --- Mixer ---
  hipLaunchKernelGGL(img_to_tokens, dim3(32, 16, BB), dim3(32, 8), 0, stream, fused, jt);
  hipLaunchKernelGGL(ln_rows_bf, dim3(MTOK), dim3(128), 0, stream, jt, ln1, xb);
  hipLaunchKernelGGL(gemm_qkv, dim3(12, 33), dim3(256), 0, stream, xb, wqkv_bf, qhB, khB, vhB);
  hipLaunchKernelGGL(transp_v, dim3(34, 2, 32), dim3(32, 8), 0, stream, vhB, vTB);
  hipLaunchKernelGGL(attn_mfma, dim3(65, 8, BB), dim3(64), 0, stream, qhB, khB, vTB, jdv, gp_weight, ao);
  hipLaunchKernelGGL(gemm_res, dim3(4, 33), dim3(256), 0, stream, ao, wo_bf, jt, (const float*)nullptr, 512);
  hipLaunchKernelGGL(ln_rows_bf, dim3(MTOK), dim3(128), 0, stream, jt, ln2, xb);
  hipLaunchKernelGGL(gemm_gelu_bf, dim3(8, 33), dim3(256), 0, stream, xb, w1_bf, mlp_b1, hb);
  hipLaunchKernelGGL(gemm_res, dim3(4, 33), dim3(256), 0, stream, hb, w2_bf, jt, mlp_b2, 1024);

  // --- out_proj ---
  hipLaunchKernelGGL(tokens_to_img, dim3(32, 16, BB), dim3(32, 8), 0, stream, jt, Bf);
  hipLaunchKernelGGL(dw_bn_gelu, dim3(BB * CH), dim3(256), 0, stream, Bf, op_dw_w, op_bn1, dwA);
  hipLaunchKernelGGL(c2t, dim3(32, 16, BB), dim3(32, 8), 0, stream, dwA, dwT);
  hipLaunchKernelGGL(gemm_pw<1>, dim3(4, 32), dim3(256), 0, stream, dwT, opw_bf, op_bn2, fused, out);
}

// Round 4
// 389.171 us; speedup vs baseline: 2.8058x; 1.2053x over previous
//
#include <hip/hip_runtime.h>
#include <math.h>

typedef __attribute__((ext_vector_type(8))) short bf16x8;
typedef __attribute__((ext_vector_type(4))) float f32x4;

#define CH 512
#define HWP 1024
#define NTOK 1032
#define NTP 1088
#define NPRM 8
#define BB 4
#define EPSV 1e-5f
#define MTOK 4128
#define MPAD 4224

__device__ __forceinline__ float gelu_f(float x) {
  return 0.5f * x * (1.0f + erff(x * 0.70710678118654752440f));
}

__device__ __forceinline__ ushort f2bf(float x) {
  union { float f; unsigned u; } v; v.f = x;
  unsigned r = v.u + 0x7FFF + ((v.u >> 16) & 1);
  return (ushort)(r >> 16);
}

__device__ __forceinline__ float bf2f(ushort u) {
  union { unsigned u; float f; } v; v.u = ((unsigned)u) << 16;
  return v.f;
}

// async global->LDS, 16B per lane. LDS dest must be wave-uniform base; HW adds lane*16.
__device__ __forceinline__ void gl16(const ushort* g, ushort* s) {
  __builtin_amdgcn_global_load_lds(
      (const __attribute__((address_space(1))) unsigned int*)g,
      (__attribute__((address_space(3))) unsigned int*)s,
      16, 0, 0);
}

// ---------------- weight fp32 -> bf16 (packed arena) ----------------
// wqkv (786432) | wo (262144) | w1 (524288) | w2 (524288) | pgw (262144) | opw (262144) | gpw (512)
__global__ __launch_bounds__(256) void convw(
    const float* __restrict__ wq, const float* __restrict__ wk, const float* __restrict__ wv,
    const float* __restrict__ wo, const float* __restrict__ w1, const float* __restrict__ w2,
    const float* __restrict__ pgw, const float* __restrict__ opw, const float* __restrict__ gpw,
    ushort* __restrict__ out)
{
  const int total = 2621952;
  for (int i = blockIdx.x * 256 + threadIdx.x; i < total; i += gridDim.x * 256) {
    const float* src; int off;
    if (i < 262144)       { src = wq;  off = i; }
    else if (i < 524288)  { src = wk;  off = i - 262144; }
    else if (i < 786432)  { src = wv;  off = i - 524288; }
    else if (i < 1048576) { src = wo;  off = i - 786432; }
    else if (i < 1572864) { src = w1;  off = i - 1048576; }
    else if (i < 2097152) { src = w2;  off = i - 1572864; }
    else if (i < 2359296) { src = pgw; off = i - 2097152; }
    else if (i < 2621440) { src = opw; off = i - 2359296; }
    else                  { src = gpw; off = i - 2621440; }
    out[i] = f2bf(src[off]);
  }
}

// ---------------- fused dw3x3 + BN + GELU + transpose -> bf16 [b*hw][c] ----------------
__global__ __launch_bounds__(256) void dwt_fused(
    const float* __restrict__ in, const float* __restrict__ w9p,
    const float* __restrict__ bn, ushort* __restrict__ outT)
{
  __shared__ float tile[32][33];
  const int y = blockIdx.x;           // image row
  const int c0 = blockIdx.y * 32;
  const int b = blockIdx.z;
  const int tx = threadIdx.x, ty = threadIdx.y;
  #pragma unroll
  for (int i = 0; i < 4; ++i) {
    int c = c0 + ty + i * 8;
    const float* ip = in + ((size_t)(b * CH + c)) * HWP;
    const float* wp = w9p + c * 9;
    float acc = 0.0f;
    #pragma unroll
    for (int dy = 0; dy < 3; ++dy) {
      int yy = y + dy - 1;
      if ((unsigned)yy < 32u) {
        #pragma unroll
        for (int dx = 0; dx < 3; ++dx) {
          int xx = tx + dx - 1;
          if ((unsigned)xx < 32u) acc += ip[yy * 32 + xx] * wp[dy * 3 + dx];
        }
      }
    }
    float g = bn[c], be = bn[CH + c], mm = bn[2 * CH + c], vv = bn[3 * CH + c];
    float s = g * rsqrtf(vv + EPSV);
    tile[ty + i * 8][tx] = gelu_f(acc * s + (be - mm * s));
  }
  __syncthreads();
  #pragma unroll
  for (int i = 0; i < 4; ++i)
    outT[((size_t)(b * HWP + y * 32 + ty + i * 8)) * CH + c0 + tx] = f2bf(tile[tx][ty + i * 8]);
}

// ---------------- GEMM 64x64 tile, BK=64, dbuf, global_load_lds ----------------
// LDS layout per 64x64 bf16 tile: [kb(0..7)][row(0..63)][8] (kb = k/8)
__device__ __forceinline__ void stage2(const ushort* ga, const ushort* gb,
                                       ushort* la, ushort* lb, int w)
{
  gl16(ga + w * 8,       la + w * 512);
  gl16(ga + (w + 4) * 8, la + (w + 4) * 512);
  gl16(gb + w * 8,       lb + w * 512);
  gl16(gb + (w + 4) * 8, lb + (w + 4) * 512);
}

__device__ __forceinline__ void comp64(const ushort* la, const ushort* lb,
                                       int wr, int wc, int l, f32x4 (&acc)[2][2])
{
  bf16x8 af[2][2], bfv[2][2];
  #pragma unroll
  for (int ks = 0; ks < 2; ++ks) {
    int kb = ks * 4 + (l >> 4);
    #pragma unroll
    for (int mf = 0; mf < 2; ++mf)
      af[mf][ks] = *(const bf16x8*)(la + (kb * 64 + wr + mf * 16 + (l & 15)) * 8);
    #pragma unroll
    for (int nf = 0; nf < 2; ++nf)
      bfv[nf][ks] = *(const bf16x8*)(lb + (kb * 64 + wc + nf * 16 + (l & 15)) * 8);
  }
  #pragma unroll
  for (int mf = 0; mf < 2; ++mf) {
    #pragma unroll
    for (int nf = 0; nf < 2; ++nf) {
      acc[mf][nf] = __builtin_amdgcn_mfma_f32_16x16x32_bf16(af[mf][0], bfv[nf][0], acc[mf][nf], 0, 0, 0);
      acc[mf][nf] = __builtin_amdgcn_mfma_f32_16x16x32_bf16(af[mf][1], bfv[nf][1], acc[mf][nf], 0, 0, 0);
    }
  }
}

// Arow/Brow: per-lane row pointers (row = tile_base + (threadIdx.x & 63), stride = Kdim).
#define G64_PRE(Arow, Brow, Kdim) \
  __shared__ ushort sA[8192], sB[8192]; \
  f32x4 acc[2][2]; \
  { f32x4 z = {0.f, 0.f, 0.f, 0.f}; acc[0][0] = z; acc[0][1] = z; acc[1][0] = z; acc[1][1] = z; } \
  const int l = threadIdx.x & 63, w = threadIdx.x >> 6; \
  const int wr = (w >> 1) * 32, wc = (w & 1) * 32; \
  stage2(Arow, Brow, sA, sB, w); \
  __syncthreads(); \
  const int nk = (Kdim) / 64; \
  for (int kt = 0; kt < nk; ++kt) { \
    if (kt + 1 < nk) \
      stage2(Arow + (kt + 1) * 64, Brow + (kt + 1) * 64, \
             sA + ((kt + 1) & 1) * 4096, sB + ((kt + 1) & 1) * 4096, w); \
    comp64(sA + (kt & 1) * 4096, sB + (kt & 1) * 4096, wr, wc, l, acc); \
    __syncthreads(); \
  }

// QKV fused: A=xb [MPAD][512], B=wqkv [1536][512]; q/k -> [bh][tok][64], v -> [bh][64][tok]
__global__ __launch_bounds__(256) void gemm_qkv64(
    const ushort* __restrict__ A, const ushort* __restrict__ B,
    ushort* __restrict__ qh, ushort* __restrict__ kh, ushort* __restrict__ vt)
{
  const int n0 = blockIdx.x * 64, m0 = blockIdx.y * 64;
  const ushort* Arow = A + ((size_t)m0 + (threadIdx.x & 63)) * 512;
  const ushort* Brow = B + ((size_t)n0 + (threadIdx.x & 63)) * 512;
  G64_PRE(Arow, Brow, 512)
  #pragma unroll
  for (int nf = 0; nf < 2; ++nf) {
    int n = n0 + wc + nf * 16 + (l & 15);
    #pragma unroll
    for (int mf = 0; mf < 2; ++mf) {
      #pragma unroll
      for (int r = 0; r < 4; ++r) {
        int m = m0 + wr + mf * 16 + (l >> 4) * 4 + r;
        if (m < MTOK) {
          int b = m / NTOK;
          int tok = m - b * NTOK;
          float val = acc[mf][nf][r];
          if (n < 512) {
            qh[((size_t)((b * 8 + (n >> 6)) * NTP) + tok) * 64 + (n & 63)] = f2bf(val);
          } else if (n < 1024) {
            int n2 = n - 512;
            kh[((size_t)((b * 8 + (n2 >> 6)) * NTP) + tok) * 64 + (n2 & 63)] = f2bf(val);
          } else {
            int n2 = n - 1024;
            vt[((size_t)((b * 8 + (n2 >> 6)) * 64) + (n2 & 63)) * NTP + tok] = f2bf(val);
          }
        }
      }
    }
  }
}

// residual: jt[m*512+n] += acc + bias
__global__ __launch_bounds__(256) void gemm_res64(
    const ushort* __restrict__ A, const ushort* __restrict__ B,
    float* __restrict__ Cf, const float* __restrict__ bias, int Kdim)
{
  const int n0 = blockIdx.x * 64, m0 = blockIdx.y * 64;
  const ushort* Arow = A + ((size_t)m0 + (threadIdx.x & 63)) * Kdim;
  const ushort* Brow = B + ((size_t)n0 + (threadIdx.x & 63)) * Kdim;
  G64_PRE(Arow, Brow, Kdim)
  #pragma unroll
  for (int nf = 0; nf < 2; ++nf) {
    int n = n0 + wc + nf * 16 + (l & 15);
    float bv = bias ? bias[n] : 0.0f;
    #pragma unroll
    for (int mf = 0; mf < 2; ++mf) {
      #pragma unroll
      for (int r = 0; r < 4; ++r) {
        int m = m0 + wr + mf * 16 + (l >> 4) * 4 + r;
        if (m < MTOK) Cf[(size_t)m * 512 + n] += acc[mf][nf][r] + bv;
      }
    }
  }
}

// mlp1: bias + gelu -> bf16 [m][1024]
__global__ __launch_bounds__(256) void gemm_gelu64(
    const ushort* __restrict__ A, const ushort* __restrict__ B,
    const float* __restrict__ bias, ushort* __restrict__ Ob)
{
  const int n0 = blockIdx.x * 64, m0 = blockIdx.y * 64;
  const ushort* Arow = A + ((size_t)m0 + (threadIdx.x & 63)) * 512;
  const ushort* Brow = B + ((size_t)n0 + (threadIdx.x & 63)) * 512;
  G64_PRE(Arow, Brow, 512)
  #pragma unroll
  for (int nf = 0; nf < 2; ++nf) {
    int n = n0 + wc + nf * 16 + (l & 15);
    float bv = bias[n];
    #pragma unroll
    for (int mf = 0; mf < 2; ++mf) {
      #pragma unroll
      for (int r = 0; r < 4; ++r) {
        int m = m0 + wr + mf * 16 + (l >> 4) * 4 + r;
        if (m < MTOK) Ob[(size_t)m * 1024 + n] = f2bf(gelu_f(acc[mf][nf][r] + bv));
      }
    }
  }
}

// pointwise conv: A = W[o][c], B = act[b*hw][c]; out f32 [b][o][hw] coalesced.
// MODE 0: BN+GELU; MODE 1: BN + residual add
template<int MODE>
__global__ __launch_bounds__(256) void gemm_pw64(
    const ushort* __restrict__ A, const ushort* __restrict__ B,
    const float* __restrict__ bnp, const float* __restrict__ res, float* __restrict__ Of)
{
  const int hw0 = blockIdx.x * 64, m0 = blockIdx.y * 64;
  const int b = blockIdx.z;
  const ushort* Arow = A + ((size_t)m0 + (threadIdx.x & 63)) * 512;
  const ushort* Brow = B + ((size_t)(b * HWP + hw0) + (threadIdx.x & 63)) * 512;
  G64_PRE(Arow, Brow, 512)
  #pragma unroll
  for (int mf = 0; mf < 2; ++mf) {
    #pragma unroll
    for (int r = 0; r < 4; ++r) {
      int o = m0 + wr + mf * 16 + (l >> 4) * 4 + r;
      float g = bnp[o], be = bnp[CH + o], mm = bnp[2 * CH + o], vv = bnp[3 * CH + o];
      float s = g * rsqrtf(vv + EPSV);
      float sh = be - mm * s;
      #pragma unroll
      for (int nf = 0; nf < 2; ++nf) {
        int hw = hw0 + wc + nf * 16 + (l & 15);
        float x = acc[mf][nf][r] * s + sh;
        size_t oi = ((size_t)(b * CH + o)) * HWP + hw;
        if (MODE == 0) Of[oi] = gelu_f(x);
        else Of[oi] = x + res[oi];
      }
    }
  }
}

// ---------------- pp pooling ([b][c][hw] f32 -> [b*8][c]) ----------------
__global__ __launch_bounds__(128) void pp_pool(const float* __restrict__ pp, float* __restrict__ ppool)
{
  int bc = blockIdx.x;
  int b = bc >> 9, c = bc & 511;
  __shared__ float sums[8];
  if (threadIdx.x < 8) sums[threadIdx.x] = 0.0f;
  __syncthreads();
  const float* ip = pp + (size_t)bc * HWP;
  float s0 = 0.0f, s1 = 0.0f;
  #pragma unroll
  for (int kq = 0; kq < 8; ++kq) {
    float val = ip[threadIdx.x + kq * 128];
    if (kq < 4) s0 += val; else s1 += val;
  }
  int pxr = (threadIdx.x & 31) >> 3;
  atomicAdd(&sums[pxr], s0);
  atomicAdd(&sums[4 + pxr], s1);
  __syncthreads();
  if (threadIdx.x < 8)
    ppool[((size_t)b * 8 + threadIdx.x) * CH + c] = sums[threadIdx.x] * (1.0f / 128.0f);
}

// ---------------- prompt: + embed, LN -> jt rows 0..7 ----------------
__global__ __launch_bounds__(128) void prompt_ln(
    const float* __restrict__ ppool, const float* __restrict__ embed,
    const float* __restrict__ lnp, float* __restrict__ jt)
{
  int rB = blockIdx.x;
  int b = rB >> 3, pI = rB & 7;
  float4 val = ((const float4*)(ppool + (size_t)rB * CH))[threadIdx.x];
  float4 e = ((const float4*)(embed + (size_t)pI * CH))[threadIdx.x];
  val.x += e.x; val.y += e.y; val.z += e.z; val.w += e.w;
  float sum = val.x + val.y + val.z + val.w;
  float sq = val.x * val.x + val.y * val.y + val.z * val.z + val.w * val.w;
  #pragma unroll
  for (int off = 1; off < 64; off <<= 1) { sum += __shfl_xor(sum, off); sq += __shfl_xor(sq, off); }
  __shared__ float s2[4];
  if ((threadIdx.x & 63) == 0) { s2[(threadIdx.x >> 6) * 2] = sum; s2[(threadIdx.x >> 6) * 2 + 1] = sq; }
  __syncthreads();
  sum = s2[0] + s2[2]; sq = s2[1] + s2[3];
  float mu = sum * (1.0f / 512.0f);
  float var = sq * (1.0f / 512.0f) - mu * mu;
  float rstd = rsqrtf(var + EPSV);
  int c = threadIdx.x * 4;
  float4 o;
  o.x = (val.x - mu) * rstd * lnp[c] + lnp[CH + c];
  o.y = (val.y - mu) * rstd * lnp[c + 1] + lnp[CH + c + 1];
  o.z = (val.z - mu) * rstd * lnp[c + 2] + lnp[CH + c + 2];
  o.w = (val.w - mu) * rstd * lnp[c + 3] + lnp[CH + c + 3];
  ((float4*)(jt + ((size_t)(b * NTOK + pI)) * CH))[threadIdx.x] = o;
}

// ---------------- gp 1-chan pw from bf16 [b*hw][c]: row dot ----------------
__global__ __launch_bounds__(256) void gp_dot(
    const ushort* __restrict__ xT, const ushort* __restrict__ wbf,
    const float* __restrict__ b0, float* __restrict__ jdv)
{
  const int b = blockIdx.y;
  const int row0 = blockIdx.x * 16;
  const int l = threadIdx.x & 63, w = threadIdx.x >> 6;
  bf16x8 wv = *(const bf16x8*)(wbf + l * 8);
  float wf[8];
  #pragma unroll
  for (int j = 0; j < 8; ++j) wf[j] = bf2f((ushort)wv[j]);
  #pragma unroll
  for (int rr = 0; rr < 4; ++rr) {
    int hw = row0 + w * 4 + rr;
    bf16x8 xv = *(const bf16x8*)(xT + ((size_t)(b * HWP + hw)) * CH + l * 8);
    float s = 0.0f;
    #pragma unroll
    for (int j = 0; j < 8; ++j) s += wf[j] * bf2f((ushort)xv[j]);
    #pragma unroll
    for (int off = 1; off < 64; off <<= 1) s += __shfl_xor(s, off);
    if (l == 0) jdv[b * NTP + NPRM + hw] = s + b0[0];
  }
}

__global__ __launch_bounds__(256) void jd_pool(float* jd)
{
  int b = blockIdx.x;
  __shared__ float sums[8];
  if (threadIdx.x < 8) sums[threadIdx.x] = 0.0f;
  __syncthreads();
  #pragma unroll
  for (int kq = 0; kq < 4; ++kq) {
    int px = threadIdx.x + kq * 256;
    int y = px >> 5, x = px & 31;
    int r = (y >> 4) * 4 + (x >> 3);
    atomicAdd(&sums[r], jd[b * NTP + NPRM + px]);
  }
  __syncthreads();
  if (threadIdx.x < 8) jd[b * NTP + threadIdx.x] = sums[threadIdx.x] * (1.0f / 128.0f);
}

// ---------------- img tokens transpose ----------------
__global__ __launch_bounds__(256) void img_to_tokens(const float* __restrict__ fused, float* __restrict__ jt)
{
  __shared__ float tile[32][33];
  int hw0 = blockIdx.x * 32, c0 = blockIdx.y * 32, b = blockIdx.z;
  int tx = threadIdx.x, ty = threadIdx.y;
  #pragma unroll
  for (int i = 0; i < 4; ++i)
    tile[ty + i * 8][tx] = fused[((size_t)(b * CH + c0 + ty + i * 8)) * HWP + hw0 + tx];
  __syncthreads();
  #pragma unroll
  for (int i = 0; i < 4; ++i)
    jt[((size_t)(b * NTOK + NPRM + hw0 + ty + i * 8)) * CH + c0 + tx] = tile[tx][ty + i * 8];
}

__global__ __launch_bounds__(256) void tokens_to_img(const float* __restrict__ jt, float* __restrict__ out)
{
  __shared__ float tile[32][33];
  int hw0 = blockIdx.x * 32, c0 = blockIdx.y * 32, b = blockIdx.z;
  int tx = threadIdx.x, ty = threadIdx.y;
  #pragma unroll
  for (int i = 0; i < 4; ++i)
    tile[ty + i * 8][tx] = jt[((size_t)(b * NTOK + NPRM + hw0 + ty + i * 8)) * CH + c0 + tx];
  __syncthreads();
  #pragma unroll
  for (int i = 0; i < 4; ++i)
    out[((size_t)(b * CH + c0 + ty + i * 8)) * HWP + hw0 + tx] = tile[tx][ty + i * 8];
}

// ---------------- row LayerNorm -> bf16 ----------------
__global__ __launch_bounds__(128) void ln_rows_bf(
    const float* __restrict__ in, const float* __restrict__ lnp, ushort* __restrict__ out)
{
  int row = blockIdx.x;
  float4 val = ((const float4*)(in + (size_t)row * CH))[threadIdx.x];
  float sum = val.x + val.y + val.z + val.w;
  float sq = val.x * val.x + val.y * val.y + val.z * val.z + val.w * val.w;
  #pragma unroll
  for (int off = 1; off < 64; off <<= 1) { sum += __shfl_xor(sum, off); sq += __shfl_xor(sq, off); }
  __shared__ float s2[4];
  if ((threadIdx.x & 63) == 0) { s2[(threadIdx.x >> 6) * 2] = sum; s2[(threadIdx.x >> 6) * 2 + 1] = sq; }
  __syncthreads();
  sum = s2[0] + s2[2]; sq = s2[1] + s2[3];
  float mu = sum * (1.0f / 512.0f);
  float var = sq * (1.0f / 512.0f) - mu * mu;
  float rstd = rsqrtf(var + EPSV);
  int c = threadIdx.x * 4;
  ushort4 o;
  o.x = f2bf((val.x - mu) * rstd * lnp[c] + lnp[CH + c]);
  o.y = f2bf((val.y - mu) * rstd * lnp[c + 1] + lnp[CH + c + 1]);
  o.z = f2bf((val.z - mu) * rstd * lnp[c + 2] + lnp[CH + c + 2]);
  o.w = f2bf((val.w - mu) * rstd * lnp[c + 3] + lnp[CH + c + 3]);
  *(ushort4*)(out + (size_t)row * CH + c) = o;
}

// ---------------- MFMA flash attention, 4 waves, LDS-staged K/V ----------------
__device__ __forceinline__ void tok_coord(int idx, float& y, float& x)
{
  if (idx < NPRM) { y = (float)(idx >> 2); x = (float)(idx & 3) * (1.0f / 3.0f); }
  else { int t = idx - NPRM; y = (float)(t >> 5) * (1.0f / 31.0f); x = (float)(t & 31) * (1.0f / 31.0f); }
}

__global__ __launch_bounds__(256) void attn_mfma2(
    const ushort* __restrict__ qh, const ushort* __restrict__ kh,
    const ushort* __restrict__ vT, const float* __restrict__ jd,
    const float* __restrict__ gw, ushort* __restrict__ ao)
{
  __shared__ ushort sK[8192], sV[8192];
  __shared__ ushort Pl[4][16][72];
  const int t = threadIdx.x, l = t & 63, w = t >> 6;
  const int h = blockIdx.y, b = blockIdx.z;
  const int i0 = blockIdx.x * 64 + w * 16;
  const ushort* Q = qh + (size_t)(b * 8 + h) * NTP * 64;
  const ushort* K = kh + (size_t)(b * 8 + h) * NTP * 64;
  const ushort* V = vT + (size_t)(b * 8 + h) * 64 * NTP;
  const float decay = logf(1.0f - exp2f(-1.0f - 0.5f * (float)h));
  const float g0 = gw[0] * decay, g1 = gw[1] * decay;

  bf16x8 qf0 = *(const bf16x8*)(Q + (size_t)(i0 + (l & 15)) * 64 + (l >> 4) * 8);
  bf16x8 qf1 = *(const bf16x8*)(Q + (size_t)(i0 + (l & 15)) * 64 + 32 + (l >> 4) * 8);

  float yi[4], xi[4], jdi[4];
  #pragma unroll
  for (int r = 0; r < 4; ++r) {
    int i = i0 + (l >> 4) * 4 + r;
    tok_coord(i, yi[r], xi[r]);
    jdi[r] = jd[b * NTP + i];
  }

  float m_r[4] = { -1e30f, -1e30f, -1e30f, -1e30f };
  float l_r[4] = { 0.f, 0.f, 0.f, 0.f };
  f32x4 of[4];
  { f32x4 z = {0.f, 0.f, 0.f, 0.f};
    #pragma unroll
    for (int d = 0; d < 4; ++d) of[d] = z; }

#define ASTAGE(buf, j0s) { \
    const ushort* gk = K + (size_t)((j0s) + l) * 64; \
    const ushort* gv = V + (size_t)l * NTP + (j0s); \
    gl16(gk + w * 8,       sK + (buf) * 4096 + w * 512); \
    gl16(gk + (w + 4) * 8, sK + (buf) * 4096 + (w + 4) * 512); \
    gl16(gv + w * 8,       sV + (buf) * 4096 + w * 512); \
    gl16(gv + (w + 4) * 8, sV + (buf) * 4096 + (w + 4) * 512); }

  ASTAGE(0, 0)
  __syncthreads();
  const int NJT = 17;
  for (int jti = 0; jti < NJT; ++jti) {
    const int j0 = jti * 64;
    if (jti + 1 < NJT) ASTAGE((jti + 1) & 1, j0 + 64)
    const ushort* bK = sK + (jti & 1) * 4096;
    const ushort* bV = sV + (jti & 1) * 4096;

    f32x4 sfr[4];
    #pragma unroll
    for (int jf = 0; jf < 4; ++jf) {
      bf16x8 k0 = *(const bf16x8*)(bK + (((l >> 4)) * 64 + jf * 16 + (l & 15)) * 8);
      bf16x8 k1 = *(const bf16x8*)(bK + ((4 + (l >> 4)) * 64 + jf * 16 + (l & 15)) * 8);
      f32x4 z = {0.f, 0.f, 0.f, 0.f};
      z = __builtin_amdgcn_mfma_f32_16x16x32_bf16(qf0, k0, z, 0, 0, 0);
      z = __builtin_amdgcn_mfma_f32_16x16x32_bf16(qf1, k1, z, 0, 0, 0);
      sfr[jf] = z;
    }
    float pvv[4][4];
    float mt[4] = { -1e30f, -1e30f, -1e30f, -1e30f };
    #pragma unroll
    for (int jf = 0; jf < 4; ++jf) {
      int jj = j0 + jf * 16 + (l & 15);
      float yj, xj;
      tok_coord(jj, yj, xj);
      float jdj = jd[b * NTP + jj];
      bool valid = jj < NTOK;
      #pragma unroll
      for (int r = 0; r < 4; ++r) {
        float bias = g0 * (fabsf(yi[r] - yj) + fabsf(xi[r] - xj)) + g1 * fabsf(jdi[r] - jdj);
        float sv = valid ? (sfr[jf][r] * 0.125f + bias) : -1e30f;
        pvv[jf][r] = sv;
        mt[r] = fmaxf(mt[r], sv);
      }
    }
    #pragma unroll
    for (int r = 0; r < 4; ++r) {
      #pragma unroll
      for (int off = 1; off < 16; off <<= 1) mt[r] = fmaxf(mt[r], __shfl_xor(mt[r], off));
    }
    float alpha[4], ls[4];
    #pragma unroll
    for (int r = 0; r < 4; ++r) {
      float mn = fmaxf(m_r[r], mt[r]);
      alpha[r] = __expf(m_r[r] - mn);
      m_r[r] = mn;
      ls[r] = 0.f;
    }
    #pragma unroll
    for (int jf = 0; jf < 4; ++jf) {
      #pragma unroll
      for (int r = 0; r < 4; ++r) {
        float pp = __expf(pvv[jf][r] - m_r[r]);
        pvv[jf][r] = pp;
        ls[r] += pp;
      }
    }
    #pragma unroll
    for (int r = 0; r < 4; ++r) {
      #pragma unroll
      for (int off = 1; off < 16; off <<= 1) ls[r] += __shfl_xor(ls[r], off);
      l_r[r] = l_r[r] * alpha[r] + ls[r];
    }
    #pragma unroll
    for (int d = 0; d < 4; ++d) {
      #pragma unroll
      for (int r = 0; r < 4; ++r) of[d][r] *= alpha[r];
    }
    #pragma unroll
    for (int jf = 0; jf < 4; ++jf) {
      #pragma unroll
      for (int r = 0; r < 4; ++r)
        Pl[w][(l >> 4) * 4 + r][jf * 16 + (l & 15)] = f2bf(pvv[jf][r]);
    }
    asm volatile("s_waitcnt lgkmcnt(0)" ::: "memory");
    bf16x8 pa0 = *(const bf16x8*)&Pl[w][l & 15][(l >> 4) * 8];
    bf16x8 pa1 = *(const bf16x8*)&Pl[w][l & 15][32 + (l >> 4) * 8];
    #pragma unroll
    for (int df = 0; df < 4; ++df) {
      bf16x8 v0 = *(const bf16x8*)(bV + (((l >> 4)) * 64 + df * 16 + (l & 15)) * 8);
      bf16x8 v1 = *(const bf16x8*)(bV + ((4 + (l >> 4)) * 64 + df * 16 + (l & 15)) * 8);
      of[df] = __builtin_amdgcn_mfma_f32_16x16x32_bf16(pa0, v0, of[df], 0, 0, 0);
      of[df] = __builtin_amdgcn_mfma_f32_16x16x32_bf16(pa1, v1, of[df], 0, 0, 0);
    }
    __syncthreads();
  }
  #pragma unroll
  for (int r = 0; r < 4; ++r) {
    int i = i0 + (l >> 4) * 4 + r;
    if (i < NTOK) {
      float inv = 1.0f / l_r[r];
      #pragma unroll
      for (int df = 0; df < 4; ++df)
        ao[((size_t)(b * NTOK + i)) * 512 + h * 64 + df * 16 + (l & 15)] = f2bf(of[df][r] * inv);
    }
  }
}

// ---------------- host ----------------
extern "C" void kernel_launch(void* const* d_in, const int* in_sizes, int n_in,
                              void* d_out, int out_size, void* d_ws, size_t ws_size,
                              hipStream_t stream)
{
  const float* fused = (const float*)d_in[0];
  const float* depth = (const float*)d_in[1];
  const float* pg_dw_w = (const float*)d_in[2];
  const float* pg_bn1 = (const float*)d_in[3];
  const float* pg_pw_w = (const float*)d_in[4];
  const float* pg_bn2 = (const float*)d_in[5];
  const float* prompt_embed = (const float*)d_in[6];
  const float* pg_ln = (const float*)d_in[7];
  const float* gp_dw_w = (const float*)d_in[8];
  const float* gp_bn = (const float*)d_in[9];
  const float* gp_pw_w = (const float*)d_in[10];
  const float* gp_pw_b = (const float*)d_in[11];
  const float* gp_weight = (const float*)d_in[12];
  const float* ln1 = (const float*)d_in[13];
  const float* wq = (const float*)d_in[14];
  const float* wk = (const float*)d_in[15];
  const float* wv = (const float*)d_in[16];
  const float* wo = (const float*)d_in[17];
  const float* ln2 = (const float*)d_in[18];
  const float* mlp_w1 = (const float*)d_in[19];
  const float* mlp_b1 = (const float*)d_in[20];
  const float* mlp_w2 = (const float*)d_in[21];
  const float* mlp_b2 = (const float*)d_in[22];
  const float* op_dw_w = (const float*)d_in[23];
  const float* op_bn1 = (const float*)d_in[24];
  const float* op_pw_w = (const float*)d_in[25];
  const float* op_bn2 = (const float*)d_in[26];
  float* out = (float*)d_out;

  char* p = (char*)d_ws;
  auto alloc = [&](size_t bytes) { char* r = p; p += (bytes + 1023) & ~(size_t)1023; return r; };
  float*  jt    = (float*) alloc((size_t)MTOK * 512 * 4);
  ushort* xb    = (ushort*)alloc((size_t)MPAD * 512 * 2);
  ushort* hb    = (ushort*)alloc((size_t)MPAD * 1024 * 2);
  ushort* ao    = (ushort*)alloc((size_t)MPAD * 512 * 2);
  ushort* qhB   = (ushort*)alloc((size_t)32 * NTP * 64 * 2);
  ushort* khB   = (ushort*)alloc((size_t)32 * NTP * 64 * 2);
  ushort* vTB   = (ushort*)alloc((size_t)32 * NTP * 64 * 2);
  ushort* dwT1  = (ushort*)alloc((size_t)BB * HWP * CH * 2);
  ushort* dwT2  = (ushort*)alloc((size_t)BB * HWP * CH * 2);
  float*  ppf   = (float*) alloc((size_t)BB * CH * HWP * 4);
  float*  Bf    = (float*) alloc((size_t)BB * CH * HWP * 4);
  float*  jdv   = (float*) alloc((size_t)BB * NTP * 4);
  float*  ppool = (float*) alloc((size_t)BB * 8 * CH * 4);
  ushort* wbf   = (ushort*)alloc((size_t)2621952 * 2);

  ushort* wqkv_bf = wbf;
  ushort* wo_bf   = wbf + 786432;
  ushort* w1_bf   = wbf + 1048576;
  ushort* w2_bf   = wbf + 1572864;
  ushort* pgw_bf  = wbf + 2097152;
  ushort* opw_bf  = wbf + 2359296;
  ushort* gpw_bf  = wbf + 2621440;

  hipLaunchKernelGGL(convw, dim3(4096), dim3(256), 0, stream,
                     wq, wk, wv, wo, mlp_w1, mlp_w2, pg_pw_w, op_pw_w, gp_pw_w, wbf);

  // --- DepthPromptGenerator ---
  hipLaunchKernelGGL(dwt_fused, dim3(32, 16, BB), dim3(32, 8), 0, stream, depth, pg_dw_w, pg_bn1, dwT1);
  hipLaunchKernelGGL(gemm_pw64<0>, dim3(16, 8, BB), dim3(256), 0, stream, pgw_bf, dwT1, pg_bn2, (const float*)nullptr, ppf);
  hipLaunchKernelGGL(pp_pool, dim3(BB * CH), dim3(128), 0, stream, ppf, ppool);
  hipLaunchKernelGGL(prompt_ln, dim3(BB * NPRM), dim3(128), 0, stream, ppool, prompt_embed, pg_ln, jt);

  // --- GeometryPriorGenerator ---
  hipLaunchKernelGGL(dwt_fused, dim3(32, 16, BB), dim3(32, 8), 0, stream, depth, gp_dw_w, gp_bn, dwT2);
  hipLaunchKernelGGL(gp_dot, dim3(64, BB), dim3(256), 0, stream, dwT2, gpw_bf, gp_pw_b, jdv);
  hipLaunchKernelGGL(jd_pool, dim3(BB), dim3(256), 0, stream, jdv);

  // --- Mixer ---
  hipLaunchKernelGGL(img_to_tokens, dim3(32, 16, BB), dim3(32, 8), 0, stream, fused, jt);
  hipLaunchKernelGGL(ln_rows_bf, dim3(MTOK), dim3(128), 0, stream, jt, ln1, xb);
  hipLaunchKernelGGL(gemm_qkv64, dim3(24, 65), dim3(256), 0, stream, xb, wqkv_bf, qhB, khB, vTB);
  hipLaunchKernelGGL(attn_mfma2, dim3(17, 8, BB), dim3(256), 0, stream, qhB, khB, vTB, jdv, gp_weight, ao);
  hipLaunchKernelGGL(gemm_res64, dim3(8, 65), dim3(256), 0, stream, ao, wo_bf, jt, (const float*)nullptr, 512);
  hipLaunchKernelGGL(ln_rows_bf, dim3(MTOK), dim3(128), 0, stream, jt, ln2, xb);
  hipLaunchKernelGGL(gemm_gelu64, dim3(16, 65), dim3(256), 0, stream, xb, w1_bf, mlp_b1, hb);
  hipLaunchKernelGGL(gemm_res64, dim3(8, 65), dim3(256), 0, stream, hb, w2_bf, jt, mlp_b2, 1024);

  // --- out_proj ---
  hipLaunchKernelGGL(tokens_to_img, dim3(32, 16, BB), dim3(32, 8), 0, stream, jt, Bf);
  hipLaunchKernelGGL(dwt_fused, dim3(32, 16, BB), dim3(32, 8), 0, stream, Bf, op_dw_w, op_bn1, dwT1);
  hipLaunchKernelGGL(gemm_pw64<1>, dim3(16, 8, BB), dim3(256), 0, stream, opw_bf, dwT1, op_bn2, fused, out);
}